// Round 8
// baseline (8379.939 us; speedup 1.0000x reference)
//
#include <hip/hip_runtime.h>
#include <cstdint>
#include <cstddef>

#define T_LEN 2048
#define BATCH 128

__device__ __forceinline__ float bcast(float v, int l) {
  return __uint_as_float(__builtin_amdgcn_readlane(__float_as_uint(v), (unsigned)l));
}
__device__ __forceinline__ float sigm(float x) {
  return __builtin_amdgcn_rcpf(1.0f + exp2f(-1.4426950408889634f * x));
}
__device__ __forceinline__ float tanh_fast(float x) {
  return 1.0f - 2.0f * __builtin_amdgcn_rcpf(1.0f + exp2f(2.8853900817779268f * x));
}

#define BAR()                                              \
  do {                                                     \
    asm volatile("s_waitcnt lgkmcnt(0)" ::: "memory");     \
    __builtin_amdgcn_s_barrier();                          \
    asm volatile("" ::: "memory");                         \
  } while (0)

// ---------------- proj: in0[t*B+b, j] = relu(x[b,t,:] . w_proj[j,:] + b_proj[j])
__global__ __launch_bounds__(256) void proj_kernel(
    const float* __restrict__ x, const float* __restrict__ w_proj,
    const float* __restrict__ b_proj, float* __restrict__ in0) {
  int R = blockIdx.x * 4 + (threadIdx.x >> 6);  // R = t*BATCH + b
  int j = threadIdx.x & 63;
  int t = R >> 7;
  int b = R & 127;
  const float* xr = x + ((size_t)b * T_LEN + t) * 32;
  const float* wr = w_proj + j * 32;
  float a = b_proj[j];
#pragma unroll
  for (int k = 0; k < 32; ++k) a = fmaf(xr[k], wr[k], a);
  in0[(size_t)R * 64 + j] = fmaxf(a, 0.f);
}

// ================= CHUNKED PRE PATH =================
// pre_gemm_chunk: PC[r][g'] = bias[g'] + A[rowmap(r)][:].W[g'][:]
// PC has C*B rows. Col tiles y<4 (fwd, cols 0..255): rowmap = baseF + r.
// Col tiles y>=4 (bwd, cols 256..511): rowmap = baseB - (r>>7)*128 + (r&127),
// i.e. the bwd direction's t-reversed chunk. 4x4 register microtile, 64x64
// output tile, K staged in 64-wide slices (pad 68: aligned b128, 2-way banks).
template <int K>
__global__ __launch_bounds__(256) void pre_gemm_chunk(
    const float* __restrict__ A,     // [T*B][K] (global rows)
    const float* __restrict__ W,     // [512][K]
    const float* __restrict__ bias,  // [512]
    float* __restrict__ PC,          // [C*B][512]
    long baseF, long baseB)
{
  __shared__ float At[64][68];  // [k][row]
  __shared__ float Wt[64][68];  // [k][col]
  const int tid = threadIdx.x;
  const int r0 = blockIdx.x * 64;         // local PC row base
  const int c0 = blockIdx.y * 64;         // output col base
  const bool rev = blockIdx.y >= 4;
  const int tx = tid & 15, ty = tid >> 4; // 16x16 thread grid
  const int rc = tid & 63, kg = tid >> 6; // staging mapping

  // global A row for local row (r0+rc)
  long rowg;
  {
    int r = r0 + rc;
    int cch = r >> 7, bb = r & 127;
    rowg = rev ? (baseB - (long)cch * 128 + bb) : (baseF + r);
  }
  const long wrow = c0 + rc;

  float acc[4][4];
#pragma unroll
  for (int i = 0; i < 4; ++i)
#pragma unroll
    for (int jx = 0; jx < 4; ++jx) acc[i][jx] = 0.f;

#pragma unroll
  for (int kb = 0; kb < K; kb += 64) {
    if (kb) __syncthreads();
    // stage 64 rows x 64 k of A and W (per-lane rows, conflict-free writes)
#pragma unroll
    for (int q = 0; q < 4; ++q) {
      int kl = 4 * (kg + 4 * q);
      float4 va = *(const float4*)(A + rowg * K + kb + kl);
      At[kl + 0][rc] = va.x; At[kl + 1][rc] = va.y;
      At[kl + 2][rc] = va.z; At[kl + 3][rc] = va.w;
      float4 vw = *(const float4*)(W + wrow * K + kb + kl);
      Wt[kl + 0][rc] = vw.x; Wt[kl + 1][rc] = vw.y;
      Wt[kl + 2][rc] = vw.z; Wt[kl + 3][rc] = vw.w;
    }
    __syncthreads();
#pragma unroll 16
    for (int k = 0; k < 64; ++k) {
      float4 a4 = *(const float4*)&At[k][4 * ty];
      float4 w4 = *(const float4*)&Wt[k][4 * tx];
      acc[0][0] = fmaf(a4.x, w4.x, acc[0][0]); acc[0][1] = fmaf(a4.x, w4.y, acc[0][1]);
      acc[0][2] = fmaf(a4.x, w4.z, acc[0][2]); acc[0][3] = fmaf(a4.x, w4.w, acc[0][3]);
      acc[1][0] = fmaf(a4.y, w4.x, acc[1][0]); acc[1][1] = fmaf(a4.y, w4.y, acc[1][1]);
      acc[1][2] = fmaf(a4.y, w4.z, acc[1][2]); acc[1][3] = fmaf(a4.y, w4.w, acc[1][3]);
      acc[2][0] = fmaf(a4.z, w4.x, acc[2][0]); acc[2][1] = fmaf(a4.z, w4.y, acc[2][1]);
      acc[2][2] = fmaf(a4.z, w4.z, acc[2][2]); acc[2][3] = fmaf(a4.z, w4.w, acc[2][3]);
      acc[3][0] = fmaf(a4.w, w4.x, acc[3][0]); acc[3][1] = fmaf(a4.w, w4.y, acc[3][1]);
      acc[3][2] = fmaf(a4.w, w4.z, acc[3][2]); acc[3][3] = fmaf(a4.w, w4.w, acc[3][3]);
    }
  }
  float4 bv = *(const float4*)&bias[c0 + 4 * tx];
#pragma unroll
  for (int i = 0; i < 4; ++i) {
    float4 o;
    o.x = acc[i][0] + bv.x; o.y = acc[i][1] + bv.y;
    o.z = acc[i][2] + bv.z; o.w = acc[i][3] + bv.w;
    *(float4*)&PC[(size_t)(r0 + 4 * ty + i) * 512 + c0 + 4 * tx] = o;
  }
}

// lstm_seq_chunk: one wave per (b,dir) chain, advances C steps. Zero barriers,
// zero cross-wave traffic. Lane j owns hidden unit j (gate rows {j,64+j,128+j,
// 192+j} of w_hh in 256 VGPR); h broadcast via in-wave LDS write + uniform
// b128 reads (same-wave DS ops program-ordered). pre streamed via 4-deep
// statically-indexed register ring. (h,c) carried across chunks in `state`.
__global__ __launch_bounds__(64, 1) void lstm_seq_chunk(
    const float* __restrict__ PC,    // [C*B][512], bias folded in
    const float* __restrict__ w_hh,  // [2][256][64]
    float* __restrict__ out,         // [T*B][128]
    float* __restrict__ state,       // [256][128] : h then c per chain
    int C, int k)
{
  const int dir = blockIdx.x & 1;
  const int b = blockIdx.x >> 1;
  const int j = threadIdx.x;
  __shared__ float hb[64];

  float4 wi[16], wf[16], wg[16], wo[16];
  {
    const float4* qi = (const float4*)(w_hh + (size_t)(dir * 256 + 0 + j) * 64);
    const float4* qf = (const float4*)(w_hh + (size_t)(dir * 256 + 64 + j) * 64);
    const float4* qg = (const float4*)(w_hh + (size_t)(dir * 256 + 128 + j) * 64);
    const float4* qo = (const float4*)(w_hh + (size_t)(dir * 256 + 192 + j) * 64);
#pragma unroll
    for (int kk = 0; kk < 16; ++kk) {
      wi[kk] = qi[kk]; wf[kk] = qf[kk]; wg[kk] = qg[kk]; wo[kk] = qo[kk];
    }
  }
  float h, c;
  if (k == 0) {
    h = 0.f; c = 0.f;
  } else {
    h = state[blockIdx.x * 128 + j];
    c = state[blockIdx.x * 128 + 64 + j];
  }
  hb[j] = h;
  const int base = dir * 256 + j;
  const long tb0 = (long)k * C;  // global step base

  float ring[4][4];
#pragma unroll
  for (int p = 0; p < 4; ++p) {
    const float* pp = PC + ((size_t)p * 128 + b) * 512 + base;
    ring[p][0] = pp[0]; ring[p][1] = pp[64]; ring[p][2] = pp[128]; ring[p][3] = pp[192];
  }

  for (int t4 = 0; t4 < C / 4; ++t4) {
#pragma unroll
    for (int p = 0; p < 4; ++p) {
      const int s = t4 * 4 + p;
      float zi = ring[p][0], zf = ring[p][1], zg = ring[p][2], zo = ring[p][3];
      if (s + 4 < C) {
        const float* pp = PC + ((size_t)(s + 4) * 128 + b) * 512 + base;
        ring[p][0] = pp[0]; ring[p][1] = pp[64]; ring[p][2] = pp[128]; ring[p][3] = pp[192];
      }
#pragma unroll
      for (int kk = 0; kk < 16; ++kk) {
        float4 h4 = *(const float4*)&hb[4 * kk];
        zi = fmaf(h4.x, wi[kk].x, zi); zf = fmaf(h4.x, wf[kk].x, zf);
        zg = fmaf(h4.x, wg[kk].x, zg); zo = fmaf(h4.x, wo[kk].x, zo);
        zi = fmaf(h4.y, wi[kk].y, zi); zf = fmaf(h4.y, wf[kk].y, zf);
        zg = fmaf(h4.y, wg[kk].y, zg); zo = fmaf(h4.y, wo[kk].y, zo);
        zi = fmaf(h4.z, wi[kk].z, zi); zf = fmaf(h4.z, wf[kk].z, zf);
        zg = fmaf(h4.z, wg[kk].z, zg); zo = fmaf(h4.z, wo[kk].z, zo);
        zi = fmaf(h4.w, wi[kk].w, zi); zf = fmaf(h4.w, wf[kk].w, zf);
        zg = fmaf(h4.w, wg[kk].w, zg); zo = fmaf(h4.w, wo[kk].w, zo);
      }
      float ig = sigm(zi), fg = sigm(zf), gg = tanh_fast(zg), og = sigm(zo);
      c = fmaf(fg, c, ig * gg);
      h = og * tanh_fast(c);
      hb[j] = h;  // next step's reads are program-ordered after this
      long tg = dir ? (T_LEN - 1 - (tb0 + s)) : (tb0 + s);
      out[((size_t)tg * BATCH + b) * 128 + dir * 64 + j] = h;
    }
  }
  state[blockIdx.x * 128 + j] = h;
  state[blockIdx.x * 128 + 64 + j] = c;
}

// ================= OLD PATH (R6, fallback if ws too small) =================
template <int DIN>
__global__ __attribute__((amdgpu_flat_work_group_size(768, 768),
                          amdgpu_waves_per_eu(3)))
void lstm_kernel(
    const float* __restrict__ in, float* __restrict__ out,
    const float* __restrict__ w_ih, const float* __restrict__ w_hh,
    const float* __restrict__ bias) {
  constexpr int KW = DIN / 4;
  constexpr int NF4W = KW / 4;
  constexpr int SREG = 16 * DIN / 512;
  constexpr int IREG = 32 * DIN / 512;
  const int LEAD = 4;
  const int tid = threadIdx.x;
  const int dir = blockIdx.x & 1;
  const int b = blockIdx.x >> 1;
  const bool is_prod = tid >= 256;
  const int ptid = tid - 256;
  const int pw = ptid >> 6;
  const int og = pw & 1;
  const int ks = pw >> 1;
  const int l = tid & 63;
  const int cw = tid >> 6;
  const int oh = cw & 1;
  const int kh = cw >> 1;
  const int r0 = oh * 128 + l;
  const int r1 = oh * 128 + 64 + l;

  __shared__ float xring[32][DIN];
  __shared__ float preh[8][4][256];
  __shared__ float zb[2][256][2];

  float4 w[16];
  float bz0 = 0.f, bz1 = 0.f;
  if (is_prod) {
    const float4* q0 = (const float4*)(w_ih + (size_t)(dir * 256 + og * 128 + l) * DIN + KW * ks);
    const float4* q1 = (const float4*)(w_ih + (size_t)(dir * 256 + og * 128 + 64 + l) * DIN + KW * ks);
#pragma unroll
    for (int k = 0; k < NF4W; ++k) w[k] = q0[k];
#pragma unroll
    for (int k = 0; k < NF4W; ++k) w[NF4W + k] = q1[k];
  } else {
    const float4* q0 = (const float4*)(w_hh + (size_t)(dir * 256 + r0) * 64 + kh * 32);
    const float4* q1 = (const float4*)(w_hh + (size_t)(dir * 256 + r1) * 64 + kh * 32);
#pragma unroll
    for (int k = 0; k < 8; ++k) w[k] = q0[k];
#pragma unroll
    for (int k = 0; k < 8; ++k) w[8 + k] = q1[k];
    if (kh == 0) {
      bz0 = bias[dir * 256 + r0];
      bz1 = bias[dir * 256 + r1];
    }
  }
  if (is_prod) {
#pragma unroll
    for (int q = 0; q < IREG; ++q) {
      int idx = ptid + 512 * q;
      int r = idx / DIN;
      int col = idx % DIN;
      int t = dir ? (T_LEN - 1 - r) : r;
      xring[r][col] = in[((size_t)t * BATCH + b) * DIN + col];
    }
  }
  __syncthreads();

  float c = 0.f, h = 0.f;
  float stg[SREG];
  const int rlbase = __builtin_amdgcn_readfirstlane((ks * KW) & 63);
  const bool xhigh = (ks * KW) >= 64;

  for (int i = 0; i < T_LEN + LEAD; ++i) {
    if (is_prod) {
      if (i < T_LEN) {
        if ((i & 15) == 0 && i > 0 && i + 16 < T_LEN) {
#pragma unroll
          for (int q = 0; q < SREG; ++q) {
            int idx = ptid + 512 * q;
            int r = i + 16 + idx / DIN;
            int col = idx % DIN;
            int t = dir ? (T_LEN - 1 - r) : r;
            stg[q] = in[((size_t)t * BATCH + b) * DIN + col];
          }
        }
        const int slot = i & 31;
        float xv0 = xring[slot][l];
        float xs;
        if constexpr (DIN == 128) {
          float xv1 = xring[slot][64 + l];
          xs = xhigh ? xv1 : xv0;
        } else {
          xs = xv0;
        }
        const float* wf = (const float*)w;
        float a0 = 0.f, a1 = 0.f;
#pragma unroll
        for (int k = 0; k < KW; ++k) {
          float sx = bcast(xs, rlbase + k);
          a0 = fmaf(sx, wf[k], a0);
          a1 = fmaf(sx, wf[KW + k], a1);
        }
        preh[i & 7][ks][og * 128 + l] = a0;
        preh[i & 7][ks][og * 128 + 64 + l] = a1;
        if ((i & 15) == 8 && i > 8 && (i - 8) + 16 < T_LEN) {
#pragma unroll
          for (int q = 0; q < SREG; ++q) {
            int idx = ptid + 512 * q;
            int r = (i - 8) + 16 + idx / DIN;
            int col = idx % DIN;
            xring[r & 31][col] = stg[q];
          }
        }
      }
    } else {
      int s = i - LEAD;
      if (s >= 0) {
        float pr0 = preh[s & 7][2 * kh + 0][r0];
        float pr1 = preh[s & 7][2 * kh + 1][r0];
        float pr2 = preh[s & 7][2 * kh + 0][r1];
        float pr3 = preh[s & 7][2 * kh + 1][r1];
        if (s > 0) {
          const float2* zp = (const float2*)&zb[(s - 1) & 1][0][0];
          float2 vi = zp[l];
          float2 vf = zp[64 + l];
          float2 vg = zp[128 + l];
          float2 vo = zp[192 + l];
          float zi = vi.x + vi.y, zf = vf.x + vf.y;
          float zg = vg.x + vg.y, zo = vo.x + vo.y;
          float ig = sigm(zi), fg = sigm(zf), gg = tanh_fast(zg), og_ = sigm(zo);
          c = fmaf(fg, c, ig * gg);
          h = og_ * tanh_fast(c);
          if (tid < 64) {
            int tp = dir ? (T_LEN - s) : (s - 1);
            out[((size_t)tp * BATCH + b) * 128 + dir * 64 + l] = h;
          }
        }
        float p0 = (bz0 + pr0) + pr1;
        float p1 = (bz1 + pr2) + pr3;
        const float* wf = (const float*)w;
        if (kh == 0) {
#pragma unroll
          for (int k = 0; k < 32; ++k) {
            float sx = bcast(h, k);
            p0 = fmaf(sx, wf[k], p0);
            p1 = fmaf(sx, wf[32 + k], p1);
          }
        } else {
#pragma unroll
          for (int k = 0; k < 32; ++k) {
            float sx = bcast(h, 32 + k);
            p0 = fmaf(sx, wf[k], p0);
            p1 = fmaf(sx, wf[32 + k], p1);
          }
        }
        zb[s & 1][r0][kh] = p0;
        zb[s & 1][r1][kh] = p1;
      }
    }
    BAR();
  }
  if (tid < 64) {
    const int pb = (T_LEN - 1) & 1;
    const float2* zp = (const float2*)&zb[pb][0][0];
    float2 vi = zp[l];
    float2 vf = zp[64 + l];
    float2 vg = zp[128 + l];
    float2 vo = zp[192 + l];
    float zi = vi.x + vi.y, zf = vf.x + vf.y;
    float zg = vg.x + vg.y, zo = vo.x + vo.y;
    float ig = sigm(zi), fg = sigm(zf), gg = tanh_fast(zg), og_ = sigm(zo);
    c = fmaf(fg, c, ig * gg);
    h = og_ * tanh_fast(c);
    int tp = dir ? 0 : (T_LEN - 1);
    out[((size_t)tp * BATCH + b) * 128 + dir * 64 + l] = h;
  }
}

// ---------------- attention
__global__ __launch_bounds__(256) void attn_kernel(
    const float* __restrict__ hs, const float* __restrict__ w_attn,
    float* __restrict__ pooled) {
  const int b = blockIdx.x, tid = threadIdx.x;
  __shared__ float wa[128];
  __shared__ float sc[T_LEN];
  __shared__ float red[256];
  if (tid < 128) wa[tid] = w_attn[tid];
  __syncthreads();

  float lmax = -3.4e38f;
#pragma unroll
  for (int i = 0; i < T_LEN / 256; ++i) {
    int t = tid + 256 * i;
    const float4* r4 = (const float4*)(hs + ((size_t)t * BATCH + b) * 128);
    float s = 0.f;
#pragma unroll
    for (int k = 0; k < 32; ++k) {
      float4 v = r4[k];
      s += v.x * wa[4 * k] + v.y * wa[4 * k + 1] + v.z * wa[4 * k + 2] + v.w * wa[4 * k + 3];
    }
    sc[t] = s;
    lmax = fmaxf(lmax, s);
  }
  red[tid] = lmax;
  __syncthreads();
  for (int off = 128; off > 0; off >>= 1) {
    if (tid < off) red[tid] = fmaxf(red[tid], red[tid + off]);
    __syncthreads();
  }
  float m = red[0];
  __syncthreads();

  float lsum = 0.f;
#pragma unroll
  for (int i = 0; i < T_LEN / 256; ++i) {
    int t = tid + 256 * i;
    float e = exp2f((sc[t] - m) * 1.4426950408889634f);
    sc[t] = e;
    lsum += e;
  }
  red[tid] = lsum;
  __syncthreads();
  for (int off = 128; off > 0; off >>= 1) {
    if (tid < off) red[tid] += red[tid + off];
    __syncthreads();
  }
  float inv = __builtin_amdgcn_rcpf(red[0]);

  if (tid < 128) {
    float a0 = 0.f, a1 = 0.f, a2 = 0.f, a3 = 0.f;
    for (int t = 0; t < T_LEN; t += 4) {
      a0 = fmaf(sc[t], hs[((size_t)t * BATCH + b) * 128 + tid], a0);
      a1 = fmaf(sc[t + 1], hs[((size_t)(t + 1) * BATCH + b) * 128 + tid], a1);
      a2 = fmaf(sc[t + 2], hs[((size_t)(t + 2) * BATCH + b) * 128 + tid], a2);
      a3 = fmaf(sc[t + 3], hs[((size_t)(t + 3) * BATCH + b) * 128 + tid], a3);
    }
    pooled[b * 128 + tid] = ((a0 + a1) + (a2 + a3)) * inv;
  }
}

// ---------------- head
__global__ __launch_bounds__(128) void head_kernel(
    const float* __restrict__ pooled,
    const float* g1, const float* be1, const float* m1, const float* v1,
    const float* w1, const float* b1, const float* w2, const float* b2,
    const float* g2, const float* be2, const float* m2, const float* v2,
    const float* w3, const float* b3, float* __restrict__ out) {
  const int b = blockIdx.x, tid = threadIdx.x;
  __shared__ float xb[128], y1[128], y2[64];
  xb[tid] = (pooled[b * 128 + tid] - m1[tid]) * rsqrtf(v1[tid] + 1e-5f) * g1[tid] + be1[tid];
  __syncthreads();
  float a = b1[tid];
#pragma unroll 8
  for (int k = 0; k < 128; ++k) a = fmaf(xb[k], w1[tid * 128 + k], a);
  y1[tid] = fmaxf(a, 0.f);
  __syncthreads();
  if (tid < 64) {
    float a2 = b2[tid];
#pragma unroll 8
    for (int k = 0; k < 128; ++k) a2 = fmaf(y1[k], w2[tid * 128 + k], a2);
    if (a2 < 0.f) a2 = exp2f(a2 * 1.4426950408889634f) - 1.0f;  // elu
    y2[tid] = (a2 - m2[tid]) * rsqrtf(v2[tid] + 1e-5f) * g2[tid] + be2[tid];
  }
  __syncthreads();
  if (tid < 3) {
    float a3 = b3[tid];
#pragma unroll
    for (int k = 0; k < 64; ++k) a3 = fmaf(y2[k], w3[tid * 64 + k], a3);
    out[b * 3 + tid] = a3;
  }
}

extern "C" void kernel_launch(void* const* d_in, const int* in_sizes, int n_in,
                              void* d_out, int out_size, void* d_ws, size_t ws_size,
                              hipStream_t stream) {
  const float* x      = (const float*)d_in[0];
  const float* w_proj = (const float*)d_in[1];
  const float* b_proj = (const float*)d_in[2];
  const float* w_ih_l0 = (const float*)d_in[3];
  const float* w_hh_l0 = (const float*)d_in[4];
  const float* b_l0    = (const float*)d_in[5];
  const float* w_ih_r  = (const float*)d_in[6];  // [3,2,256,128]
  const float* w_hh_r  = (const float*)d_in[7];  // [3,2,256,64]
  const float* b_r     = (const float*)d_in[8];  // [3,2,256]
  const float* w_attn  = (const float*)d_in[9];
  const float* g1  = (const float*)d_in[11];
  const float* be1 = (const float*)d_in[12];
  const float* m1  = (const float*)d_in[13];
  const float* v1  = (const float*)d_in[14];
  const float* w1  = (const float*)d_in[15];
  const float* b1  = (const float*)d_in[16];
  const float* w2  = (const float*)d_in[17];
  const float* b2  = (const float*)d_in[18];
  const float* g2  = (const float*)d_in[19];
  const float* be2 = (const float*)d_in[20];
  const float* m2  = (const float*)d_in[21];
  const float* v2  = (const float*)d_in[22];
  const float* w3  = (const float*)d_in[23];
  const float* b3  = (const float*)d_in[24];
  float* out = (float*)d_out;

  const size_t BUF_FLOATS = (size_t)T_LEN * BATCH * 128;  // 134 MB
  const size_t STATE_FLOATS = 256 * 128;                  // 128 KB

  // pick largest chunk C (steps) whose PC buffer fits after 2 bufs + state
  int C = 0;
  for (int cc = T_LEN; cc >= 16; cc >>= 1) {
    size_t need = (2 * BUF_FLOATS + STATE_FLOATS + (size_t)cc * BATCH * 512) * sizeof(float);
    if (need <= ws_size) { C = cc; break; }
  }

  if (C) {
    // ---- chunked precomputed-pre GEMM + barrier-free single-wave recurrence
    float* bufA  = (float*)d_ws;
    float* bufB  = bufA + BUF_FLOATS;
    float* state = bufB + BUF_FLOATS;
    float* PC    = state + STATE_FLOATS;
    float* in0 = bufB;     // [T,B,64]; dead once layer1 writes bufB
    float* pooled = bufA;  // dead region after last layer reads bufA

    proj_kernel<<<T_LEN * BATCH / 4, 256, 0, stream>>>(x, w_proj, b_proj, in0);

    const int NCH = T_LEN / C;
    dim3 gg(C * BATCH / 64, 8);

    // layer 0 (K=64): in0 -> bufA
    for (int k = 0; k < NCH; ++k) {
      long baseF = (long)k * C * BATCH;
      long baseB = (long)(T_LEN - 1 - k * C) * BATCH;
      pre_gemm_chunk<64><<<gg, 256, 0, stream>>>(in0, w_ih_l0, b_l0, PC, baseF, baseB);
      lstm_seq_chunk<<<256, 64, 0, stream>>>(PC, w_hh_l0, bufA, state, C, k);
    }
    // layers 1..3 (K=128)
    const float* WIH[3] = {w_ih_r, w_ih_r + 65536, w_ih_r + 131072};
    const float* WHH[3] = {w_hh_r, w_hh_r + 32768, w_hh_r + 65536};
    const float* BB[3]  = {b_r, b_r + 512, b_r + 1024};
    float* IO[4] = {bufA, bufB, bufA, bufB};
    for (int l = 0; l < 3; ++l) {
      for (int k = 0; k < NCH; ++k) {
        long baseF = (long)k * C * BATCH;
        long baseB = (long)(T_LEN - 1 - k * C) * BATCH;
        pre_gemm_chunk<128><<<gg, 256, 0, stream>>>(IO[l], WIH[l], BB[l], PC, baseF, baseB);
        lstm_seq_chunk<<<256, 64, 0, stream>>>(PC, WHH[l], IO[l + 1], state, C, k);
      }
    }
    attn_kernel<<<BATCH, 256, 0, stream>>>(bufB, w_attn, pooled);
    head_kernel<<<BATCH, 128, 0, stream>>>(pooled, g1, be1, m1, v1, w1, b1, w2, b2,
                                           g2, be2, m2, v2, w3, b3, out);
  } else {
    // ---- fallback: R6 path (268 MB ws)
    float* bufA = (float*)d_ws;
    float* bufB = bufA + BUF_FLOATS;
    float* in0 = bufB;
    float* pooled = bufA;

    proj_kernel<<<T_LEN * BATCH / 4, 256, 0, stream>>>(x, w_proj, b_proj, in0);
    lstm_kernel<64><<<256, 768, 0, stream>>>(in0, bufA, w_ih_l0, w_hh_l0, b_l0);
    lstm_kernel<128><<<256, 768, 0, stream>>>(bufA, bufB, w_ih_r, w_hh_r, b_r);
    lstm_kernel<128><<<256, 768, 0, stream>>>(bufB, bufA, w_ih_r + 65536, w_hh_r + 32768, b_r + 512);
    lstm_kernel<128><<<256, 768, 0, stream>>>(bufA, bufB, w_ih_r + 131072, w_hh_r + 65536, b_r + 1024);
    attn_kernel<<<BATCH, 256, 0, stream>>>(bufB, w_attn, pooled);
    head_kernel<<<BATCH, 128, 0, stream>>>(pooled, g1, be1, m1, v1, w1, b1, w2, b2,
                                           g2, be2, m2, v2, w3, b3, out);
  }
}

// Round 9
// 7429.522 us; speedup vs baseline: 1.1279x; 1.1279x over previous
//
#include <hip/hip_runtime.h>
#include <cstdint>
#include <cstddef>

#define T_LEN 2048
#define BATCH 128
#define CHK 16

__device__ __forceinline__ float bcast(float v, int l) {
  return __uint_as_float(__builtin_amdgcn_readlane(__float_as_uint(v), (unsigned)l));
}
__device__ __forceinline__ float sigm(float x) {
  return __builtin_amdgcn_rcpf(1.0f + exp2f(-1.4426950408889634f * x));
}
__device__ __forceinline__ float tanh_fast(float x) {
  return 1.0f - 2.0f * __builtin_amdgcn_rcpf(1.0f + exp2f(2.8853900817779268f * x));
}

// lgkm-only fence + raw barrier: LDS writes visible across waves; global loads
// and h-stores stay in flight across the barrier.
#define BAR()                                              \
  do {                                                     \
    asm volatile("s_waitcnt lgkmcnt(0)" ::: "memory");     \
    __builtin_amdgcn_s_barrier();                          \
    asm volatile("" ::: "memory");                         \
  } while (0)

// ---------------- proj: in0[t*B+b, j] = relu(x[b,t,:] . w_proj[j,:] + b_proj[j])
__global__ __launch_bounds__(256) void proj_kernel(
    const float* __restrict__ x, const float* __restrict__ w_proj,
    const float* __restrict__ b_proj, float* __restrict__ in0) {
  int R = blockIdx.x * 4 + (threadIdx.x >> 6);  // R = t*BATCH + b
  int j = threadIdx.x & 63;
  int t = R >> 7;
  int b = R & 127;
  const float* xr = x + ((size_t)b * T_LEN + t) * 32;
  const float* wr = w_proj + j * 32;
  float a = b_proj[j];
#pragma unroll
  for (int k = 0; k < 32; ++k) a = fmaf(xr[k], wr[k], a);
  in0[(size_t)R * 64 + j] = fmaxf(a, 0.f);
}

// ================= FUSED LSTM LAYER =================
// One block per (b,dir) chain, 256 threads = 4 waves = one per SIMD.
// wave 0 (consumer): private SIMD, runs the serial recurrence. Lane j owns
//   hidden unit j and gate rows {j,64+j,128+j,192+j} (w_hh in 256 VGPR).
//   Per step: 12 LDS partial reads + 64 readlane (own-wave h!) + 256 FMA.
// waves 1-3 (producers): compute input-GEMM partials for chunk k+1 into
//   pb[(k+1)&1] (K-slices 48/48/32), and stage chunk k+2's x rows into
//   xc[k&1] (loads issued early, LDS writes late). One barrier per CHK steps.

// producer body, compile-time K-slice [LO,HI)
template <int DIN, int LO, int HI>
__device__ __forceinline__ void producer_run(
    const float* __restrict__ in, const float* __restrict__ w_ih,
    int dir, int b, int l, int ptid, int pslot,
    float (&xc)[2][CHK][DIN], float (&pb)[2][CHK][3][256]) {
  constexpr int NW = HI - LO;
  constexpr int NF4 = NW / 4;
  constexpr int NCH = T_LEN / CHK;
  constexpr int NF4C = CHK * DIN / 4;            // float4s per x chunk
  constexpr int NLD = (NF4C + 191) / 192;        // per-producer-thread loads

  float4 wreg[4 * NF4];
#pragma unroll
  for (int r = 0; r < 4; ++r) {
    const float4* q = (const float4*)(w_ih + (size_t)(dir * 256 + r * 64 + l) * DIN + LO);
#pragma unroll
    for (int k = 0; k < NF4; ++k) wreg[r * NF4 + k] = q[k];
  }
  const float* wf = (const float*)wreg;

  auto pre_compute = [&](int xb, int pbuf) {
#pragma unroll 1
    for (int s = 0; s < CHK; ++s) {
      float x0 = xc[xb][s][l];
      float x1 = 0.f;
      if constexpr (DIN == 128) x1 = xc[xb][s][64 + l];
      float a0 = 0.f, a1 = 0.f, a2 = 0.f, a3 = 0.f;
#pragma unroll
      for (int k = LO; k < HI; ++k) {
        float xs = bcast((k >= 64) ? x1 : x0, k & 63);
        a0 = fmaf(xs, wf[0 * NW + k - LO], a0);
        a1 = fmaf(xs, wf[1 * NW + k - LO], a1);
        a2 = fmaf(xs, wf[2 * NW + k - LO], a2);
        a3 = fmaf(xs, wf[3 * NW + k - LO], a3);
      }
      pb[pbuf][s][pslot][l] = a0;
      pb[pbuf][s][pslot][64 + l] = a1;
      pb[pbuf][s][pslot][128 + l] = a2;
      pb[pbuf][s][pslot][192 + l] = a3;
    }
  };

  float4 stg[NLD];
  auto issue_chunk = [&](int c) {  // global loads for x chunk c -> stg
#pragma unroll
    for (int q = 0; q < NLD; ++q) {
      int idx = ptid + 192 * q;
      if (idx < NF4C) {
        int sl = idx / (DIN / 4), col = idx % (DIN / 4);
        int sg = c * CHK + sl;
        long t = dir ? (T_LEN - 1 - sg) : sg;
        stg[q] = *(const float4*)(in + ((size_t)t * BATCH + b) * DIN + col * 4);
      }
    }
  };
  auto write_chunk = [&](int xb) {  // stg -> xc[xb]
#pragma unroll
    for (int q = 0; q < NLD; ++q) {
      int idx = ptid + 192 * q;
      if (idx < NF4C) {
        int sl = idx / (DIN / 4), col = idx % (DIN / 4);
        *(float4*)&xc[xb][sl][col * 4] = stg[q];
      }
    }
  };

  // prologue: pre[0] from xc[0]; stage x chunk 1 -> xc[1]
  issue_chunk(1);
  pre_compute(0, 0);
  write_chunk(1);
  BAR();

  for (int k = 0; k < NCH; ++k) {
    if (k + 2 < NCH) issue_chunk(k + 2);
    if (k + 1 < NCH) pre_compute((k + 1) & 1, (k + 1) & 1);
    if (k + 2 < NCH) write_chunk(k & 1);
    BAR();
  }
}

template <int DIN>
__global__ __attribute__((amdgpu_flat_work_group_size(256, 256),
                          amdgpu_waves_per_eu(1, 1)))
void lstm_fused(const float* __restrict__ in,    // [T*B][DIN]
                float* __restrict__ out,         // [T*B][128]
                const float* __restrict__ w_ih,  // [2,256,DIN]
                const float* __restrict__ w_hh,  // [2,256,64]
                const float* __restrict__ bias)  // [2,256]
{
  constexpr int NCH = T_LEN / CHK;
  constexpr int L1 = (DIN == 128) ? 48 : 24;
  constexpr int L2 = (DIN == 128) ? 96 : 48;

  const int tid = threadIdx.x;
  const int dir = blockIdx.x & 1;
  const int b = blockIdx.x >> 1;
  const int wid = tid >> 6;
  const int l = tid & 63;

  __shared__ float xc[2][CHK][DIN];        // x chunks (traversal order)
  __shared__ float pb[2][CHK][3][256];     // pre-activation partials

  // cooperative load of x chunk 0 -> xc[0]
  {
    constexpr int NF4C = CHK * DIN / 4;
#pragma unroll
    for (int q = 0; q < (NF4C + 255) / 256; ++q) {
      int idx = tid + 256 * q;
      if (idx < NF4C) {
        int sl = idx / (DIN / 4), col = idx % (DIN / 4);
        long t = dir ? (T_LEN - 1 - sl) : sl;
        *(float4*)&xc[0][sl][col * 4] =
            *(const float4*)(in + ((size_t)t * BATCH + b) * DIN + col * 4);
      }
    }
  }
  __syncthreads();

  if (wid == 1) {
    producer_run<DIN, 0, L1>(in, w_ih, dir, b, l, tid - 64, 0, xc, pb);
  } else if (wid == 2) {
    producer_run<DIN, L1, L2>(in, w_ih, dir, b, l, tid - 64, 1, xc, pb);
  } else if (wid == 3) {
    producer_run<DIN, L2, DIN>(in, w_ih, dir, b, l, tid - 64, 2, xc, pb);
  } else {
    // -------- consumer --------
    float4 wreg[64];
#pragma unroll
    for (int r = 0; r < 4; ++r) {
      const float4* q = (const float4*)(w_hh + (size_t)(dir * 256 + r * 64 + l) * 64);
#pragma unroll
      for (int k = 0; k < 16; ++k) wreg[r * 16 + k] = q[k];
    }
    const float* wf = (const float*)wreg;
    const float bz0 = bias[dir * 256 + l];
    const float bz1 = bias[dir * 256 + 64 + l];
    const float bz2 = bias[dir * 256 + 128 + l];
    const float bz3 = bias[dir * 256 + 192 + l];

    BAR();  // matches producer prologue barrier

    float h = 0.f, c = 0.f;
    for (int k = 0; k < NCH; ++k) {
      const int kb = k & 1;
#pragma unroll 1
      for (int s = 0; s < CHK; ++s) {
        // pre partials (independent of h -> issued before the dot)
        float pi0 = pb[kb][s][0][l], pi1 = pb[kb][s][1][l], pi2 = pb[kb][s][2][l];
        float pf0 = pb[kb][s][0][64 + l], pf1 = pb[kb][s][1][64 + l], pf2 = pb[kb][s][2][64 + l];
        float pg0 = pb[kb][s][0][128 + l], pg1 = pb[kb][s][1][128 + l], pg2 = pb[kb][s][2][128 + l];
        float po0 = pb[kb][s][0][192 + l], po1 = pb[kb][s][1][192 + l], po2 = pb[kb][s][2][192 + l];
        // recurrent dot: 64 readlane (own-wave h) + 256 FMA
        float a0 = 0.f, a1 = 0.f, a2 = 0.f, a3 = 0.f;
#pragma unroll
        for (int k2 = 0; k2 < 64; ++k2) {
          float hs = bcast(h, k2);
          a0 = fmaf(hs, wf[k2], a0);
          a1 = fmaf(hs, wf[64 + k2], a1);
          a2 = fmaf(hs, wf[128 + k2], a2);
          a3 = fmaf(hs, wf[192 + k2], a3);
        }
        float zi = ((bz0 + pi0) + (pi1 + pi2)) + a0;
        float zf = ((bz1 + pf0) + (pf1 + pf2)) + a1;
        float zg = ((bz2 + pg0) + (pg1 + pg2)) + a2;
        float zo = ((bz3 + po0) + (po1 + po2)) + a3;
        float ig = sigm(zi), fg = sigm(zf), gg = tanh_fast(zg), og = sigm(zo);
        c = fmaf(fg, c, ig * gg);
        h = og * tanh_fast(c);
        int sg = k * CHK + s;
        long t = dir ? (T_LEN - 1 - sg) : sg;
        out[((size_t)t * BATCH + b) * 128 + dir * 64 + l] = h;
      }
      BAR();
    }
  }
}

// ---------------- attention: scores + softmax + pooled, one block per batch row
__global__ __launch_bounds__(256) void attn_kernel(
    const float* __restrict__ hs, const float* __restrict__ w_attn,
    float* __restrict__ pooled) {
  const int b = blockIdx.x, tid = threadIdx.x;
  __shared__ float wa[128];
  __shared__ float sc[T_LEN];
  __shared__ float red[256];
  if (tid < 128) wa[tid] = w_attn[tid];
  __syncthreads();

  float lmax = -3.4e38f;
#pragma unroll
  for (int i = 0; i < T_LEN / 256; ++i) {
    int t = tid + 256 * i;
    const float4* r4 = (const float4*)(hs + ((size_t)t * BATCH + b) * 128);
    float s = 0.f;
#pragma unroll
    for (int k = 0; k < 32; ++k) {
      float4 v = r4[k];
      s += v.x * wa[4 * k] + v.y * wa[4 * k + 1] + v.z * wa[4 * k + 2] + v.w * wa[4 * k + 3];
    }
    sc[t] = s;
    lmax = fmaxf(lmax, s);
  }
  red[tid] = lmax;
  __syncthreads();
  for (int off = 128; off > 0; off >>= 1) {
    if (tid < off) red[tid] = fmaxf(red[tid], red[tid + off]);
    __syncthreads();
  }
  float m = red[0];
  __syncthreads();

  float lsum = 0.f;
#pragma unroll
  for (int i = 0; i < T_LEN / 256; ++i) {
    int t = tid + 256 * i;
    float e = exp2f((sc[t] - m) * 1.4426950408889634f);
    sc[t] = e;
    lsum += e;
  }
  red[tid] = lsum;
  __syncthreads();
  for (int off = 128; off > 0; off >>= 1) {
    if (tid < off) red[tid] += red[tid + off];
    __syncthreads();
  }
  float inv = __builtin_amdgcn_rcpf(red[0]);

  if (tid < 128) {
    float a0 = 0.f, a1 = 0.f, a2 = 0.f, a3 = 0.f;
    for (int t = 0; t < T_LEN; t += 4) {
      a0 = fmaf(sc[t], hs[((size_t)t * BATCH + b) * 128 + tid], a0);
      a1 = fmaf(sc[t + 1], hs[((size_t)(t + 1) * BATCH + b) * 128 + tid], a1);
      a2 = fmaf(sc[t + 2], hs[((size_t)(t + 2) * BATCH + b) * 128 + tid], a2);
      a3 = fmaf(sc[t + 3], hs[((size_t)(t + 3) * BATCH + b) * 128 + tid], a3);
    }
    pooled[b * 128 + tid] = ((a0 + a1) + (a2 + a3)) * inv;
  }
}

// ---------------- head: BN1 -> fc1 -> relu -> fc2 -> elu -> BN2 -> fc3
__global__ __launch_bounds__(128) void head_kernel(
    const float* __restrict__ pooled,
    const float* g1, const float* be1, const float* m1, const float* v1,
    const float* w1, const float* b1, const float* w2, const float* b2,
    const float* g2, const float* be2, const float* m2, const float* v2,
    const float* w3, const float* b3, float* __restrict__ out) {
  const int b = blockIdx.x, tid = threadIdx.x;
  __shared__ float xb[128], y1[128], y2[64];
  xb[tid] = (pooled[b * 128 + tid] - m1[tid]) * rsqrtf(v1[tid] + 1e-5f) * g1[tid] + be1[tid];
  __syncthreads();
  float a = b1[tid];
#pragma unroll 8
  for (int k = 0; k < 128; ++k) a = fmaf(xb[k], w1[tid * 128 + k], a);
  y1[tid] = fmaxf(a, 0.f);
  __syncthreads();
  if (tid < 64) {
    float a2 = b2[tid];
#pragma unroll 8
    for (int k = 0; k < 128; ++k) a2 = fmaf(y1[k], w2[tid * 128 + k], a2);
    if (a2 < 0.f) a2 = exp2f(a2 * 1.4426950408889634f) - 1.0f;  // elu
    y2[tid] = (a2 - m2[tid]) * rsqrtf(v2[tid] + 1e-5f) * g2[tid] + be2[tid];
  }
  __syncthreads();
  if (tid < 3) {
    float a3 = b3[tid];
#pragma unroll
    for (int k = 0; k < 64; ++k) a3 = fmaf(y2[k], w3[tid * 64 + k], a3);
    out[b * 3 + tid] = a3;
  }
}

extern "C" void kernel_launch(void* const* d_in, const int* in_sizes, int n_in,
                              void* d_out, int out_size, void* d_ws, size_t ws_size,
                              hipStream_t stream) {
  const float* x      = (const float*)d_in[0];
  const float* w_proj = (const float*)d_in[1];
  const float* b_proj = (const float*)d_in[2];
  const float* w_ih_l0 = (const float*)d_in[3];
  const float* w_hh_l0 = (const float*)d_in[4];
  const float* b_l0    = (const float*)d_in[5];
  const float* w_ih_r  = (const float*)d_in[6];  // [3,2,256,128]
  const float* w_hh_r  = (const float*)d_in[7];  // [3,2,256,64]
  const float* b_r     = (const float*)d_in[8];  // [3,2,256]
  const float* w_attn  = (const float*)d_in[9];
  const float* g1  = (const float*)d_in[11];
  const float* be1 = (const float*)d_in[12];
  const float* m1  = (const float*)d_in[13];
  const float* v1  = (const float*)d_in[14];
  const float* w1  = (const float*)d_in[15];
  const float* b1  = (const float*)d_in[16];
  const float* w2  = (const float*)d_in[17];
  const float* b2  = (const float*)d_in[18];
  const float* g2  = (const float*)d_in[19];
  const float* be2 = (const float*)d_in[20];
  const float* m2  = (const float*)d_in[21];
  const float* v2  = (const float*)d_in[22];
  const float* w3  = (const float*)d_in[23];
  const float* b3  = (const float*)d_in[24];
  float* out = (float*)d_out;

  // ws layout: bufA [T,B,128] | bufB [T,B,128]  (in0 and pooled overlay dead regions)
  const size_t BUF_FLOATS = (size_t)T_LEN * BATCH * 128;
  float* bufA = (float*)d_ws;
  float* bufB = bufA + BUF_FLOATS;
  float* in0 = bufB;     // [T,B,64]; dead once layer1 writes bufB
  float* pooled = bufA;  // dead region after last layer reads bufA

  proj_kernel<<<T_LEN * BATCH / 4, 256, 0, stream>>>(x, w_proj, b_proj, in0);
  lstm_fused<64><<<256, 256, 0, stream>>>(in0, bufA, w_ih_l0, w_hh_l0, b_l0);
  lstm_fused<128><<<256, 256, 0, stream>>>(bufA, bufB, w_ih_r, w_hh_r, b_r);
  lstm_fused<128><<<256, 256, 0, stream>>>(bufB, bufA, w_ih_r + 65536, w_hh_r + 32768, b_r + 512);
  lstm_fused<128><<<256, 256, 0, stream>>>(bufA, bufB, w_ih_r + 131072, w_hh_r + 65536, b_r + 1024);
  attn_kernel<<<BATCH, 256, 0, stream>>>(bufB, w_attn, pooled);
  head_kernel<<<BATCH, 128, 0, stream>>>(pooled, g1, be1, m1, v1, w1, b1, w2, b2,
                                         g2, be2, m2, v2, w3, b3, out);
}

// Round 10
// 7408.717 us; speedup vs baseline: 1.1311x; 1.0028x over previous
//
#include <hip/hip_runtime.h>
#include <cstdint>
#include <cstddef>

#define T_LEN 2048
#define BATCH 128
#define CHK 8

__device__ __forceinline__ float bcast(float v, int l) {
  return __uint_as_float(__builtin_amdgcn_readlane(__float_as_uint(v), (unsigned)l));
}
__device__ __forceinline__ float sigm(float x) {
  return __builtin_amdgcn_rcpf(1.0f + exp2f(-1.4426950408889634f * x));
}
__device__ __forceinline__ float tanh_fast(float x) {
  return 1.0f - 2.0f * __builtin_amdgcn_rcpf(1.0f + exp2f(2.8853900817779268f * x));
}

// lgkm-only fence + raw barrier: LDS writes visible across waves; global loads
// and h-stores stay in flight across the barrier.
#define BAR()                                              \
  do {                                                     \
    asm volatile("s_waitcnt lgkmcnt(0)" ::: "memory");     \
    __builtin_amdgcn_s_barrier();                          \
    asm volatile("" ::: "memory");                         \
  } while (0)

// ---------------- proj: in0[t*B+b, j] = relu(x[b,t,:] . w_proj[j,:] + b_proj[j])
__global__ __launch_bounds__(256) void proj_kernel(
    const float* __restrict__ x, const float* __restrict__ w_proj,
    const float* __restrict__ b_proj, float* __restrict__ in0) {
  int R = blockIdx.x * 4 + (threadIdx.x >> 6);  // R = t*BATCH + b
  int j = threadIdx.x & 63;
  int t = R >> 7;
  int b = R & 127;
  const float* xr = x + ((size_t)b * T_LEN + t) * 32;
  const float* wr = w_proj + j * 32;
  float a = b_proj[j];
#pragma unroll
  for (int k = 0; k < 32; ++k) a = fmaf(xr[k], wr[k], a);
  in0[(size_t)R * 64 + j] = fmaxf(a, 0.f);
}

// ================= FUSED LSTM LAYER =================
// One block per (b,dir) chain, 256 threads = 4 waves = one per SIMD.
// wave 0 (consumer): private SIMD, serial recurrence. Lane l owns hidden unit
//   l and gate rows {l,64+l,128+l,192+l}. Gates i,f weights in 128 VGPR;
//   gates g,o weights in LDS (XOR-swizzled, double-buffered b128 batches,
//   h-independent reads hidden under the dot). Keeps consumer < 256 VGPR.
// waves 1-3 (producers): input-GEMM partials for chunk k+1 into pb[(k+1)&1]
//   (K-slices), x chunk staging with early-issue/late-write. One barrier/CHK.

// producer body, compile-time K-slice [LO,HI)
template <int DIN, int LO, int HI>
__device__ __forceinline__ void producer_run(
    const float* __restrict__ in, const float* __restrict__ w_ih,
    int dir, int b, int l, int ptid, int pslot,
    float (&xc)[2][CHK][DIN], float (&pb)[2][CHK][3][256]) {
  constexpr int NW = HI - LO;
  constexpr int NF4 = NW / 4;
  constexpr int NCH = T_LEN / CHK;
  constexpr int NF4C = CHK * DIN / 4;            // float4s per x chunk
  constexpr int NLD = (NF4C + 191) / 192;        // per-producer-thread loads

  float4 wreg[4 * NF4];
#pragma unroll
  for (int r = 0; r < 4; ++r) {
    const float4* q = (const float4*)(w_ih + (size_t)(dir * 256 + r * 64 + l) * DIN + LO);
#pragma unroll
    for (int k = 0; k < NF4; ++k) wreg[r * NF4 + k] = q[k];
  }
  const float* wf = (const float*)wreg;

  auto pre_compute = [&](int xb, int pbuf) {
#pragma unroll 1
    for (int s = 0; s < CHK; ++s) {
      float x0 = xc[xb][s][l];
      float x1 = 0.f;
      if constexpr (DIN == 128) x1 = xc[xb][s][64 + l];
      float a0 = 0.f, a1 = 0.f, a2 = 0.f, a3 = 0.f;
#pragma unroll
      for (int k = LO; k < HI; ++k) {
        float xs = bcast((k >= 64) ? x1 : x0, k & 63);
        a0 = fmaf(xs, wf[0 * NW + k - LO], a0);
        a1 = fmaf(xs, wf[1 * NW + k - LO], a1);
        a2 = fmaf(xs, wf[2 * NW + k - LO], a2);
        a3 = fmaf(xs, wf[3 * NW + k - LO], a3);
      }
      pb[pbuf][s][pslot][l] = a0;
      pb[pbuf][s][pslot][64 + l] = a1;
      pb[pbuf][s][pslot][128 + l] = a2;
      pb[pbuf][s][pslot][192 + l] = a3;
    }
  };

  float4 stg[NLD];
  auto issue_chunk = [&](int c) {  // global loads for x chunk c -> stg
#pragma unroll
    for (int q = 0; q < NLD; ++q) {
      int idx = ptid + 192 * q;
      if (idx < NF4C) {
        int sl = idx / (DIN / 4), col = idx % (DIN / 4);
        int sg = c * CHK + sl;
        long t = dir ? (T_LEN - 1 - sg) : sg;
        stg[q] = *(const float4*)(in + ((size_t)t * BATCH + b) * DIN + col * 4);
      }
    }
  };
  auto write_chunk = [&](int xb) {  // stg -> xc[xb]
#pragma unroll
    for (int q = 0; q < NLD; ++q) {
      int idx = ptid + 192 * q;
      if (idx < NF4C) {
        int sl = idx / (DIN / 4), col = idx % (DIN / 4);
        *(float4*)&xc[xb][sl][col * 4] = stg[q];
      }
    }
  };

  // prologue: pre[0] from xc[0]; stage x chunk 1 -> xc[1]
  issue_chunk(1);
  pre_compute(0, 0);
  write_chunk(1);
  BAR();

  for (int k = 0; k < NCH; ++k) {
    if (k + 2 < NCH) issue_chunk(k + 2);
    if (k + 1 < NCH) pre_compute((k + 1) & 1, (k + 1) & 1);
    if (k + 2 < NCH) write_chunk(k & 1);
    BAR();
  }
}

template <int DIN>
__global__ __attribute__((amdgpu_flat_work_group_size(256, 256),
                          amdgpu_waves_per_eu(1, 1)))
void lstm_fused(const float* __restrict__ in,    // [T*B][DIN]
                float* __restrict__ out,         // [T*B][128]
                const float* __restrict__ w_ih,  // [2,256,DIN]
                const float* __restrict__ w_hh,  // [2,256,64]
                const float* __restrict__ bias)  // [2,256]
{
  constexpr int NCH = T_LEN / CHK;
  constexpr int L1 = (DIN == 128) ? 48 : 24;
  constexpr int L2 = (DIN == 128) ? 96 : 48;

  const int tid = threadIdx.x;
  const int dir = blockIdx.x & 1;
  const int b = blockIdx.x >> 1;
  const int wid = tid >> 6;
  const int l = tid & 63;

  __shared__ float xc[2][CHK][DIN];     // x chunks (traversal order)
  __shared__ float pb[2][CHK][3][256];  // pre-activation partials
  __shared__ float wgo[2][64][64];      // w_hh gates g,o; slot-swizzled

  // cooperative load of x chunk 0 -> xc[0]
  {
    constexpr int NF4C = CHK * DIN / 4;
#pragma unroll
    for (int q = 0; q < (NF4C + 255) / 256; ++q) {
      int idx = tid + 256 * q;
      if (idx < NF4C) {
        int sl = idx / (DIN / 4), col = idx % (DIN / 4);
        long t = dir ? (T_LEN - 1 - sl) : sl;
        *(float4*)&xc[0][sl][col * 4] =
            *(const float4*)(in + ((size_t)t * BATCH + b) * DIN + col * 4);
      }
    }
  }
  // cooperative load of w_hh g/o rows into wgo with XOR slot swizzle.
  // thread t: row j2=t&63, gate=(t>>6)&1 (0->g rows 128+, 1->o rows 192+),
  // half=t>>7 (slots 0..7 / 8..15). swizzled slot = slot ^ (j2&7):
  // for a fixed slot, lanes spread over 8 distinct 16B slots = 32 banks.
  {
    int j2 = tid & 63;
    int gate = (tid >> 6) & 1;
    int half = tid >> 7;
    const float4* src =
        (const float4*)(w_hh + (size_t)(dir * 256 + 128 + gate * 64 + j2) * 64);
    int swj = j2 & 7;
#pragma unroll
    for (int r = 0; r < 8; ++r) {
      int slot = half * 8 + r;
      *(float4*)&wgo[gate][j2][(slot ^ swj) * 4] = src[slot];
    }
  }
  __syncthreads();

  if (wid == 1) {
    producer_run<DIN, 0, L1>(in, w_ih, dir, b, l, tid - 64, 0, xc, pb);
  } else if (wid == 2) {
    producer_run<DIN, L1, L2>(in, w_ih, dir, b, l, tid - 64, 1, xc, pb);
  } else if (wid == 3) {
    producer_run<DIN, L2, DIN>(in, w_ih, dir, b, l, tid - 64, 2, xc, pb);
  } else {
    // -------- consumer (wave 0, private SIMD) --------
    float4 wif[32];  // gate i rows (16 f4) + gate f rows (16 f4)
    {
      const float4* qi = (const float4*)(w_hh + (size_t)(dir * 256 + l) * 64);
      const float4* qf = (const float4*)(w_hh + (size_t)(dir * 256 + 64 + l) * 64);
#pragma unroll
      for (int k = 0; k < 16; ++k) {
        wif[k] = qi[k];
        wif[16 + k] = qf[k];
      }
    }
    const float* wifF = (const float*)wif;
    const float bz0 = bias[dir * 256 + l];
    const float bz1 = bias[dir * 256 + 64 + l];
    const float bz2 = bias[dir * 256 + 128 + l];
    const float bz3 = bias[dir * 256 + 192 + l];
    const int sw = l & 7;

// swizzled g/o weight read: idx in [0,16) 16B-slots of lane l's row
#define RDW(gate, idx) \
  (*(const float4*)&wgo[gate][l][(((idx) ^ sw)) * 4])
// load one 16-k batch (Q) of g/o weights into GB/OB
#define LDGO(GB, OB, Q)                                           \
  GB[0] = RDW(0, (Q)*4 + 0); GB[1] = RDW(0, (Q)*4 + 1);           \
  GB[2] = RDW(0, (Q)*4 + 2); GB[3] = RDW(0, (Q)*4 + 3);           \
  OB[0] = RDW(1, (Q)*4 + 0); OB[1] = RDW(1, (Q)*4 + 1);           \
  OB[2] = RDW(1, (Q)*4 + 2); OB[3] = RDW(1, (Q)*4 + 3);
// consume batch Q: 16 readlane + 64 fma
#define DOT16(Q, GB, OB)                                          \
  _Pragma("unroll") for (int kk = 0; kk < 16; ++kk) {             \
    float hs = bcast(h, (Q)*16 + kk);                             \
    ai = fmaf(hs, wifF[(Q)*16 + kk], ai);                         \
    af = fmaf(hs, wifF[64 + (Q)*16 + kk], af);                    \
    ag = fmaf(hs, ((const float*)&GB[kk >> 2])[kk & 3], ag);      \
    ao = fmaf(hs, ((const float*)&OB[kk >> 2])[kk & 3], ao);      \
  }

    BAR();  // matches producer prologue barrier

    float h = 0.f, c = 0.f;
    for (int k = 0; k < NCH; ++k) {
      const int kb = k & 1;
#pragma unroll 1
      for (int s = 0; s < CHK; ++s) {
        // pre partials (independent of h)
        float pi0 = pb[kb][s][0][l], pi1 = pb[kb][s][1][l], pi2 = pb[kb][s][2][l];
        float pf0 = pb[kb][s][0][64 + l], pf1 = pb[kb][s][1][64 + l], pf2 = pb[kb][s][2][64 + l];
        float pg0 = pb[kb][s][0][128 + l], pg1 = pb[kb][s][1][128 + l], pg2 = pb[kb][s][2][128 + l];
        float po0 = pb[kb][s][0][192 + l], po1 = pb[kb][s][1][192 + l], po2 = pb[kb][s][2][192 + l];
        // recurrent dot, 4 pipelined 16-k batches (g/o weights from LDS)
        float ai = 0.f, af = 0.f, ag = 0.f, ao = 0.f;
        float4 gbA[4], obA[4], gbB[4], obB[4];
        LDGO(gbA, obA, 0)
        LDGO(gbB, obB, 1)
        DOT16(0, gbA, obA)
        LDGO(gbA, obA, 2)
        DOT16(1, gbB, obB)
        LDGO(gbB, obB, 3)
        DOT16(2, gbA, obA)
        DOT16(3, gbB, obB)
        float zi = ((bz0 + pi0) + (pi1 + pi2)) + ai;
        float zf = ((bz1 + pf0) + (pf1 + pf2)) + af;
        float zg = ((bz2 + pg0) + (pg1 + pg2)) + ag;
        float zo = ((bz3 + po0) + (po1 + po2)) + ao;
        float ig = sigm(zi), fg = sigm(zf), gg = tanh_fast(zg), og = sigm(zo);
        c = fmaf(fg, c, ig * gg);
        h = og * tanh_fast(c);
        int sg = k * CHK + s;
        long t = dir ? (T_LEN - 1 - sg) : sg;
        out[((size_t)t * BATCH + b) * 128 + dir * 64 + l] = h;
      }
      BAR();
    }
#undef RDW
#undef LDGO
#undef DOT16
  }
}

// ---------------- attention: scores + softmax + pooled, one block per batch row
__global__ __launch_bounds__(256) void attn_kernel(
    const float* __restrict__ hs, const float* __restrict__ w_attn,
    float* __restrict__ pooled) {
  const int b = blockIdx.x, tid = threadIdx.x;
  __shared__ float wa[128];
  __shared__ float sc[T_LEN];
  __shared__ float red[256];
  if (tid < 128) wa[tid] = w_attn[tid];
  __syncthreads();

  float lmax = -3.4e38f;
#pragma unroll
  for (int i = 0; i < T_LEN / 256; ++i) {
    int t = tid + 256 * i;
    const float4* r4 = (const float4*)(hs + ((size_t)t * BATCH + b) * 128);
    float s = 0.f;
#pragma unroll
    for (int k = 0; k < 32; ++k) {
      float4 v = r4[k];
      s += v.x * wa[4 * k] + v.y * wa[4 * k + 1] + v.z * wa[4 * k + 2] + v.w * wa[4 * k + 3];
    }
    sc[t] = s;
    lmax = fmaxf(lmax, s);
  }
  red[tid] = lmax;
  __syncthreads();
  for (int off = 128; off > 0; off >>= 1) {
    if (tid < off) red[tid] = fmaxf(red[tid], red[tid + off]);
    __syncthreads();
  }
  float m = red[0];
  __syncthreads();

  float lsum = 0.f;
#pragma unroll
  for (int i = 0; i < T_LEN / 256; ++i) {
    int t = tid + 256 * i;
    float e = exp2f((sc[t] - m) * 1.4426950408889634f);
    sc[t] = e;
    lsum += e;
  }
  red[tid] = lsum;
  __syncthreads();
  for (int off = 128; off > 0; off >>= 1) {
    if (tid < off) red[tid] += red[tid + off];
    __syncthreads();
  }
  float inv = __builtin_amdgcn_rcpf(red[0]);

  if (tid < 128) {
    float a0 = 0.f, a1 = 0.f, a2 = 0.f, a3 = 0.f;
    for (int t = 0; t < T_LEN; t += 4) {
      a0 = fmaf(sc[t], hs[((size_t)t * BATCH + b) * 128 + tid], a0);
      a1 = fmaf(sc[t + 1], hs[((size_t)(t + 1) * BATCH + b) * 128 + tid], a1);
      a2 = fmaf(sc[t + 2], hs[((size_t)(t + 2) * BATCH + b) * 128 + tid], a2);
      a3 = fmaf(sc[t + 3], hs[((size_t)(t + 3) * BATCH + b) * 128 + tid], a3);
    }
    pooled[b * 128 + tid] = ((a0 + a1) + (a2 + a3)) * inv;
  }
}

// ---------------- head: BN1 -> fc1 -> relu -> fc2 -> elu -> BN2 -> fc3
__global__ __launch_bounds__(128) void head_kernel(
    const float* __restrict__ pooled,
    const float* g1, const float* be1, const float* m1, const float* v1,
    const float* w1, const float* b1, const float* w2, const float* b2,
    const float* g2, const float* be2, const float* m2, const float* v2,
    const float* w3, const float* b3, float* __restrict__ out) {
  const int b = blockIdx.x, tid = threadIdx.x;
  __shared__ float xb[128], y1[128], y2[64];
  xb[tid] = (pooled[b * 128 + tid] - m1[tid]) * rsqrtf(v1[tid] + 1e-5f) * g1[tid] + be1[tid];
  __syncthreads();
  float a = b1[tid];
#pragma unroll 8
  for (int k = 0; k < 128; ++k) a = fmaf(xb[k], w1[tid * 128 + k], a);
  y1[tid] = fmaxf(a, 0.f);
  __syncthreads();
  if (tid < 64) {
    float a2 = b2[tid];
#pragma unroll 8
    for (int k = 0; k < 128; ++k) a2 = fmaf(y1[k], w2[tid * 128 + k], a2);
    if (a2 < 0.f) a2 = exp2f(a2 * 1.4426950408889634f) - 1.0f;  // elu
    y2[tid] = (a2 - m2[tid]) * rsqrtf(v2[tid] + 1e-5f) * g2[tid] + be2[tid];
  }
  __syncthreads();
  if (tid < 3) {
    float a3 = b3[tid];
#pragma unroll
    for (int k = 0; k < 64; ++k) a3 = fmaf(y2[k], w3[tid * 64 + k], a3);
    out[b * 3 + tid] = a3;
  }
}

extern "C" void kernel_launch(void* const* d_in, const int* in_sizes, int n_in,
                              void* d_out, int out_size, void* d_ws, size_t ws_size,
                              hipStream_t stream) {
  const float* x      = (const float*)d_in[0];
  const float* w_proj = (const float*)d_in[1];
  const float* b_proj = (const float*)d_in[2];
  const float* w_ih_l0 = (const float*)d_in[3];
  const float* w_hh_l0 = (const float*)d_in[4];
  const float* b_l0    = (const float*)d_in[5];
  const float* w_ih_r  = (const float*)d_in[6];  // [3,2,256,128]
  const float* w_hh_r  = (const float*)d_in[7];  // [3,2,256,64]
  const float* b_r     = (const float*)d_in[8];  // [3,2,256]
  const float* w_attn  = (const float*)d_in[9];
  const float* g1  = (const float*)d_in[11];
  const float* be1 = (const float*)d_in[12];
  const float* m1  = (const float*)d_in[13];
  const float* v1  = (const float*)d_in[14];
  const float* w1  = (const float*)d_in[15];
  const float* b1  = (const float*)d_in[16];
  const float* w2  = (const float*)d_in[17];
  const float* b2  = (const float*)d_in[18];
  const float* g2  = (const float*)d_in[19];
  const float* be2 = (const float*)d_in[20];
  const float* m2  = (const float*)d_in[21];
  const float* v2  = (const float*)d_in[22];
  const float* w3  = (const float*)d_in[23];
  const float* b3  = (const float*)d_in[24];
  float* out = (float*)d_out;

  // ws layout: bufA [T,B,128] | bufB [T,B,128]  (in0 and pooled overlay dead regions)
  const size_t BUF_FLOATS = (size_t)T_LEN * BATCH * 128;
  float* bufA = (float*)d_ws;
  float* bufB = bufA + BUF_FLOATS;
  float* in0 = bufB;     // [T,B,64]; dead once layer1 writes bufB
  float* pooled = bufA;  // dead region after last layer reads bufA

  proj_kernel<<<T_LEN * BATCH / 4, 256, 0, stream>>>(x, w_proj, b_proj, in0);
  lstm_fused<64><<<256, 256, 0, stream>>>(in0, bufA, w_ih_l0, w_hh_l0, b_l0);
  lstm_fused<128><<<256, 256, 0, stream>>>(bufA, bufB, w_ih_r, w_hh_r, b_r);
  lstm_fused<128><<<256, 256, 0, stream>>>(bufB, bufA, w_ih_r + 65536, w_hh_r + 32768, b_r + 512);
  lstm_fused<128><<<256, 256, 0, stream>>>(bufA, bufB, w_ih_r + 131072, w_hh_r + 65536, b_r + 1024);
  attn_kernel<<<BATCH, 256, 0, stream>>>(bufB, w_attn, pooled);
  head_kernel<<<BATCH, 128, 0, stream>>>(pooled, g1, be1, m1, v1, w1, b1, w2, b2,
                                         g2, be2, m2, v2, w3, b3, out);
}

// Round 11
// 7294.798 us; speedup vs baseline: 1.1488x; 1.0156x over previous
//
#include <hip/hip_runtime.h>
#include <cstdint>
#include <cstddef>

#define T_LEN 2048
#define BATCH 128
#define CHK 8

typedef float v2f __attribute__((ext_vector_type(2)));

__device__ __forceinline__ float bcast(float v, int l) {
  return __uint_as_float(__builtin_amdgcn_readlane(__float_as_uint(v), (unsigned)l));
}
__device__ __forceinline__ float sigm(float x) {
  return __builtin_amdgcn_rcpf(1.0f + exp2f(-1.4426950408889634f * x));
}
__device__ __forceinline__ float tanh_fast(float x) {
  return 1.0f - 2.0f * __builtin_amdgcn_rcpf(1.0f + exp2f(2.8853900817779268f * x));
}

// lgkm-only fence + raw barrier: LDS writes visible across waves; global loads
// and h-stores stay in flight across the barrier.
#define BAR()                                              \
  do {                                                     \
    asm volatile("s_waitcnt lgkmcnt(0)" ::: "memory");     \
    __builtin_amdgcn_s_barrier();                          \
    asm volatile("" ::: "memory");                         \
  } while (0)

// ---------------- proj: in0[t*B+b, j] = relu(x[b,t,:] . w_proj[j,:] + b_proj[j])
__global__ __launch_bounds__(256) void proj_kernel(
    const float* __restrict__ x, const float* __restrict__ w_proj,
    const float* __restrict__ b_proj, float* __restrict__ in0) {
  int R = blockIdx.x * 4 + (threadIdx.x >> 6);  // R = t*BATCH + b
  int j = threadIdx.x & 63;
  int t = R >> 7;
  int b = R & 127;
  const float* xr = x + ((size_t)b * T_LEN + t) * 32;
  const float* wr = w_proj + j * 32;
  float a = b_proj[j];
#pragma unroll
  for (int k = 0; k < 32; ++k) a = fmaf(xr[k], wr[k], a);
  in0[(size_t)R * 64 + j] = fmaxf(a, 0.f);
}

// ================= FUSED LSTM LAYER =================
// One block per (b,dir) chain, 256 threads = 4 waves = one per SIMD.
// wave 0 (consumer): private SIMD, serial recurrence, v_pk_fma_f32 dot:
//   gate pair (i,f) weights as 64 v2f in VGPR; gate pair (g,o) weights in
//   LDS (32-slot XOR swizzle, conflict-free), prefetched a half-step deep.
// waves 1-3 (producers): input-GEMM partials for chunk k+1 into pb[(k+1)&1]
//   (K-slices), x chunk staging with early-issue/late-write. One barrier/CHK.

// producer body, compile-time K-slice [LO,HI)
template <int DIN, int LO, int HI>
__device__ __forceinline__ void producer_run(
    const float* __restrict__ in, const float* __restrict__ w_ih,
    int dir, int b, int l, int ptid, int pslot,
    float (&xc)[2][CHK][DIN], float (&pb)[2][CHK][3][256]) {
  constexpr int NW = HI - LO;
  constexpr int NF4 = NW / 4;
  constexpr int NCH = T_LEN / CHK;
  constexpr int NF4C = CHK * DIN / 4;            // float4s per x chunk
  constexpr int NLD = (NF4C + 191) / 192;        // per-producer-thread loads

  float4 wreg[4 * NF4];
#pragma unroll
  for (int r = 0; r < 4; ++r) {
    const float4* q = (const float4*)(w_ih + (size_t)(dir * 256 + r * 64 + l) * DIN + LO);
#pragma unroll
    for (int k = 0; k < NF4; ++k) wreg[r * NF4 + k] = q[k];
  }
  const float* wf = (const float*)wreg;

  auto pre_compute = [&](int xb, int pbuf) {
#pragma unroll 1
    for (int s = 0; s < CHK; ++s) {
      float x0 = xc[xb][s][l];
      float x1 = 0.f;
      if constexpr (DIN == 128) x1 = xc[xb][s][64 + l];
      float a0 = 0.f, a1 = 0.f, a2 = 0.f, a3 = 0.f;
#pragma unroll
      for (int k = LO; k < HI; ++k) {
        float xs = bcast((k >= 64) ? x1 : x0, k & 63);
        a0 = fmaf(xs, wf[0 * NW + k - LO], a0);
        a1 = fmaf(xs, wf[1 * NW + k - LO], a1);
        a2 = fmaf(xs, wf[2 * NW + k - LO], a2);
        a3 = fmaf(xs, wf[3 * NW + k - LO], a3);
      }
      pb[pbuf][s][pslot][l] = a0;
      pb[pbuf][s][pslot][64 + l] = a1;
      pb[pbuf][s][pslot][128 + l] = a2;
      pb[pbuf][s][pslot][192 + l] = a3;
    }
  };

  float4 stg[NLD];
  auto issue_chunk = [&](int c) {  // global loads for x chunk c -> stg
#pragma unroll
    for (int q = 0; q < NLD; ++q) {
      int idx = ptid + 192 * q;
      if (idx < NF4C) {
        int sl = idx / (DIN / 4), col = idx % (DIN / 4);
        int sg = c * CHK + sl;
        long t = dir ? (T_LEN - 1 - sg) : sg;
        stg[q] = *(const float4*)(in + ((size_t)t * BATCH + b) * DIN + col * 4);
      }
    }
  };
  auto write_chunk = [&](int xb) {  // stg -> xc[xb]
#pragma unroll
    for (int q = 0; q < NLD; ++q) {
      int idx = ptid + 192 * q;
      if (idx < NF4C) {
        int sl = idx / (DIN / 4), col = idx % (DIN / 4);
        *(float4*)&xc[xb][sl][col * 4] = stg[q];
      }
    }
  };

  // prologue: pre[0] from xc[0]; stage x chunk 1 -> xc[1]
  issue_chunk(1);
  pre_compute(0, 0);
  write_chunk(1);
  BAR();

  for (int k = 0; k < NCH; ++k) {
    if (k + 2 < NCH) issue_chunk(k + 2);
    if (k + 1 < NCH) pre_compute((k + 1) & 1, (k + 1) & 1);
    if (k + 2 < NCH) write_chunk(k & 1);
    BAR();
  }
}

template <int DIN>
__global__ __attribute__((amdgpu_flat_work_group_size(256, 256),
                          amdgpu_waves_per_eu(1, 1)))
void lstm_fused(const float* __restrict__ in,    // [T*B][DIN]
                float* __restrict__ out,         // [T*B][128]
                const float* __restrict__ w_ih,  // [2,256,DIN]
                const float* __restrict__ w_hh,  // [2,256,64]
                const float* __restrict__ bias)  // [2,256]
{
  constexpr int NCH = T_LEN / CHK;
  constexpr int L1 = (DIN == 128) ? 48 : 24;
  constexpr int L2 = (DIN == 128) ? 96 : 48;

  const int tid = threadIdx.x;
  const int dir = blockIdx.x & 1;
  const int b = blockIdx.x >> 1;
  const int wid = tid >> 6;
  const int l = tid & 63;

  __shared__ float xc[2][CHK][DIN];     // x chunks (traversal order)
  __shared__ float pb[2][CHK][3][256];  // pre-activation partials
  __shared__ float wgo2[64][128];       // (g,o) weight pairs, XOR-swizzled

  // cooperative load of x chunk 0 -> xc[0]
  {
    constexpr int NF4C = CHK * DIN / 4;
#pragma unroll
    for (int q = 0; q < (NF4C + 255) / 256; ++q) {
      int idx = tid + 256 * q;
      if (idx < NF4C) {
        int sl = idx / (DIN / 4), col = idx % (DIN / 4);
        long t = dir ? (T_LEN - 1 - sl) : sl;
        *(float4*)&xc[0][sl][col * 4] =
            *(const float4*)(in + ((size_t)t * BATCH + b) * DIN + col * 4);
      }
    }
  }
  // wgo2 fill: row j2 holds interleaved pairs {g_row(128+j2)[k], o_row(192+j2)[k]}.
  // 16B-slot s = k/2 in [0,32) stored at physical slot s ^ (j2 & 31) (bijective
  // per row; for fixed s, 64 lanes hit 32 distinct slots -> conflict-free b128).
  {
    int j2 = tid & 63;
    int q = tid >> 6;  // k-quarter: k in [q*16, q*16+16)
    const float* gR = w_hh + (size_t)(dir * 256 + 128 + j2) * 64;
    const float* oR = w_hh + (size_t)(dir * 256 + 192 + j2) * 64;
    float4* row = (float4*)&wgo2[j2][0];
#pragma unroll
    for (int s = q * 8; s < q * 8 + 8; ++s) {
      int k = 2 * s;
      float4 v;
      v.x = gR[k]; v.y = oR[k]; v.z = gR[k + 1]; v.w = oR[k + 1];
      row[s ^ (j2 & 31)] = v;
    }
  }
  __syncthreads();

  if (wid == 1) {
    producer_run<DIN, 0, L1>(in, w_ih, dir, b, l, tid - 64, 0, xc, pb);
  } else if (wid == 2) {
    producer_run<DIN, L1, L2>(in, w_ih, dir, b, l, tid - 64, 1, xc, pb);
  } else if (wid == 3) {
    producer_run<DIN, L2, DIN>(in, w_ih, dir, b, l, tid - 64, 2, xc, pb);
  } else {
    // -------- consumer (wave 0, private SIMD) --------
    // (i,f) weight pairs in VGPR: w2if[k] = {w_hh[l][k], w_hh[64+l][k]}
    v2f w2if[64];
    {
      const float4* qi = (const float4*)(w_hh + (size_t)(dir * 256 + l) * 64);
      const float4* qf = (const float4*)(w_hh + (size_t)(dir * 256 + 64 + l) * 64);
#pragma unroll
      for (int k4 = 0; k4 < 16; ++k4) {
        float4 vi = qi[k4], vf = qf[k4];
        w2if[4 * k4 + 0] = (v2f){vi.x, vf.x};
        w2if[4 * k4 + 1] = (v2f){vi.y, vf.y};
        w2if[4 * k4 + 2] = (v2f){vi.z, vf.z};
        w2if[4 * k4 + 3] = (v2f){vi.w, vf.w};
      }
    }
    const float bz0 = bias[dir * 256 + l];
    const float bz1 = bias[dir * 256 + 64 + l];
    const float bz2 = bias[dir * 256 + 128 + l];
    const float bz3 = bias[dir * 256 + 192 + l];
    const int swz = l & 31;
    const float4* wgoRow = (const float4*)&wgo2[l][0];

    // running output pointer (no per-step 64-bit mul)
    float* outp = out + ((size_t)(dir ? (T_LEN - 1) : 0) * BATCH + b) * 128 + dir * 64 + l;
    const ptrdiff_t ostride = dir ? -(ptrdiff_t)(BATCH * 128) : (ptrdiff_t)(BATCH * 128);

    BAR();  // matches producer prologue barrier

    float h = 0.f, c = 0.f;
    for (int k = 0; k < NCH; ++k) {
      const float* pbase = &pb[k & 1][0][0][0];
#pragma unroll 1
      for (int s = 0; s < CHK; ++s) {
        const float* ps = pbase + s * (3 * 256);
        // pre partials (h-independent; issued at step top)
        float pi0 = ps[l], pi1 = ps[256 + l], pi2 = ps[512 + l];
        float pf0 = ps[64 + l], pf1 = ps[320 + l], pf2 = ps[576 + l];
        float pg0 = ps[128 + l], pg1 = ps[384 + l], pg2 = ps[640 + l];
        float po0 = ps[192 + l], po1 = ps[448 + l], po2 = ps[704 + l];

        v2f aif = (v2f){0.f, 0.f}, ago = (v2f){0.f, 0.f};
        float4 gb[16];
#pragma unroll
        for (int half = 0; half < 2; ++half) {
          // 1) issue 16 swizzled b128 reads for this half's (g,o) pairs
#pragma unroll
          for (int ss = 0; ss < 16; ++ss)
            gb[ss] = wgoRow[(half * 16 + ss) ^ swz];
          // 2) 32 readlane + 32 pk-fma on (i,f) — pure VGPR, hides LDS latency
          float hsv[32];
#pragma unroll
          for (int kk = 0; kk < 32; ++kk) hsv[kk] = bcast(h, half * 32 + kk);
#pragma unroll
          for (int kk = 0; kk < 32; ++kk) {
            v2f hp = (v2f){hsv[kk], hsv[kk]};
            aif = __builtin_elementwise_fma(hp, w2if[half * 32 + kk], aif);
          }
          // 3) consume the batch: 32 pk-fma on (g,o)
#pragma unroll
          for (int kk = 0; kk < 32; ++kk) {
            v2f hp = (v2f){hsv[kk], hsv[kk]};
            float4 q4 = gb[kk >> 1];
            v2f wp = (kk & 1) ? (v2f){q4.z, q4.w} : (v2f){q4.x, q4.y};
            ago = __builtin_elementwise_fma(hp, wp, ago);
          }
        }
        float zi = aif.x + ((bz0 + pi0) + (pi1 + pi2));
        float zf = aif.y + ((bz1 + pf0) + (pf1 + pf2));
        float zg = ago.x + ((bz2 + pg0) + (pg1 + pg2));
        float zo = ago.y + ((bz3 + po0) + (po1 + po2));
        float ig = sigm(zi), fg = sigm(zf), gg = tanh_fast(zg), og = sigm(zo);
        c = fmaf(fg, c, ig * gg);
        h = og * tanh_fast(c);
        *outp = h;
        outp += ostride;
      }
      BAR();
    }
  }
}

// ---------------- attention: scores + softmax + pooled, one block per batch row
__global__ __launch_bounds__(256) void attn_kernel(
    const float* __restrict__ hs, const float* __restrict__ w_attn,
    float* __restrict__ pooled) {
  const int b = blockIdx.x, tid = threadIdx.x;
  __shared__ float wa[128];
  __shared__ float sc[T_LEN];
  __shared__ float red[256];
  if (tid < 128) wa[tid] = w_attn[tid];
  __syncthreads();

  float lmax = -3.4e38f;
#pragma unroll
  for (int i = 0; i < T_LEN / 256; ++i) {
    int t = tid + 256 * i;
    const float4* r4 = (const float4*)(hs + ((size_t)t * BATCH + b) * 128);
    float s = 0.f;
#pragma unroll
    for (int k = 0; k < 32; ++k) {
      float4 v = r4[k];
      s += v.x * wa[4 * k] + v.y * wa[4 * k + 1] + v.z * wa[4 * k + 2] + v.w * wa[4 * k + 3];
    }
    sc[t] = s;
    lmax = fmaxf(lmax, s);
  }
  red[tid] = lmax;
  __syncthreads();
  for (int off = 128; off > 0; off >>= 1) {
    if (tid < off) red[tid] = fmaxf(red[tid], red[tid + off]);
    __syncthreads();
  }
  float m = red[0];
  __syncthreads();

  float lsum = 0.f;
#pragma unroll
  for (int i = 0; i < T_LEN / 256; ++i) {
    int t = tid + 256 * i;
    float e = exp2f((sc[t] - m) * 1.4426950408889634f);
    sc[t] = e;
    lsum += e;
  }
  red[tid] = lsum;
  __syncthreads();
  for (int off = 128; off > 0; off >>= 1) {
    if (tid < off) red[tid] += red[tid + off];
    __syncthreads();
  }
  float inv = __builtin_amdgcn_rcpf(red[0]);

  if (tid < 128) {
    float a0 = 0.f, a1 = 0.f, a2 = 0.f, a3 = 0.f;
    for (int t = 0; t < T_LEN; t += 4) {
      a0 = fmaf(sc[t], hs[((size_t)t * BATCH + b) * 128 + tid], a0);
      a1 = fmaf(sc[t + 1], hs[((size_t)(t + 1) * BATCH + b) * 128 + tid], a1);
      a2 = fmaf(sc[t + 2], hs[((size_t)(t + 2) * BATCH + b) * 128 + tid], a2);
      a3 = fmaf(sc[t + 3], hs[((size_t)(t + 3) * BATCH + b) * 128 + tid], a3);
    }
    pooled[b * 128 + tid] = ((a0 + a1) + (a2 + a3)) * inv;
  }
}

// ---------------- head: BN1 -> fc1 -> relu -> fc2 -> elu -> BN2 -> fc3
__global__ __launch_bounds__(128) void head_kernel(
    const float* __restrict__ pooled,
    const float* g1, const float* be1, const float* m1, const float* v1,
    const float* w1, const float* b1, const float* w2, const float* b2,
    const float* g2, const float* be2, const float* m2, const float* v2,
    const float* w3, const float* b3, float* __restrict__ out) {
  const int b = blockIdx.x, tid = threadIdx.x;
  __shared__ float xb[128], y1[128], y2[64];
  xb[tid] = (pooled[b * 128 + tid] - m1[tid]) * rsqrtf(v1[tid] + 1e-5f) * g1[tid] + be1[tid];
  __syncthreads();
  float a = b1[tid];
#pragma unroll 8
  for (int k = 0; k < 128; ++k) a = fmaf(xb[k], w1[tid * 128 + k], a);
  y1[tid] = fmaxf(a, 0.f);
  __syncthreads();
  if (tid < 64) {
    float a2 = b2[tid];
#pragma unroll 8
    for (int k = 0; k < 128; ++k) a2 = fmaf(y1[k], w2[tid * 128 + k], a2);
    if (a2 < 0.f) a2 = exp2f(a2 * 1.4426950408889634f) - 1.0f;  // elu
    y2[tid] = (a2 - m2[tid]) * rsqrtf(v2[tid] + 1e-5f) * g2[tid] + be2[tid];
  }
  __syncthreads();
  if (tid < 3) {
    float a3 = b3[tid];
#pragma unroll
    for (int k = 0; k < 64; ++k) a3 = fmaf(y2[k], w3[tid * 64 + k], a3);
    out[b * 3 + tid] = a3;
  }
}

extern "C" void kernel_launch(void* const* d_in, const int* in_sizes, int n_in,
                              void* d_out, int out_size, void* d_ws, size_t ws_size,
                              hipStream_t stream) {
  const float* x      = (const float*)d_in[0];
  const float* w_proj = (const float*)d_in[1];
  const float* b_proj = (const float*)d_in[2];
  const float* w_ih_l0 = (const float*)d_in[3];
  const float* w_hh_l0 = (const float*)d_in[4];
  const float* b_l0    = (const float*)d_in[5];
  const float* w_ih_r  = (const float*)d_in[6];  // [3,2,256,128]
  const float* w_hh_r  = (const float*)d_in[7];  // [3,2,256,64]
  const float* b_r     = (const float*)d_in[8];  // [3,2,256]
  const float* w_attn  = (const float*)d_in[9];
  const float* g1  = (const float*)d_in[11];
  const float* be1 = (const float*)d_in[12];
  const float* m1  = (const float*)d_in[13];
  const float* v1  = (const float*)d_in[14];
  const float* w1  = (const float*)d_in[15];
  const float* b1  = (const float*)d_in[16];
  const float* w2  = (const float*)d_in[17];
  const float* b2  = (const float*)d_in[18];
  const float* g2  = (const float*)d_in[19];
  const float* be2 = (const float*)d_in[20];
  const float* m2  = (const float*)d_in[21];
  const float* v2  = (const float*)d_in[22];
  const float* w3  = (const float*)d_in[23];
  const float* b3  = (const float*)d_in[24];
  float* out = (float*)d_out;

  // ws layout: bufA [T,B,128] | bufB [T,B,128]  (in0 and pooled overlay dead regions)
  const size_t BUF_FLOATS = (size_t)T_LEN * BATCH * 128;
  float* bufA = (float*)d_ws;
  float* bufB = bufA + BUF_FLOATS;
  float* in0 = bufB;     // [T,B,64]; dead once layer1 writes bufB
  float* pooled = bufA;  // dead region after last layer reads bufA

  proj_kernel<<<T_LEN * BATCH / 4, 256, 0, stream>>>(x, w_proj, b_proj, in0);
  lstm_fused<64><<<256, 256, 0, stream>>>(in0, bufA, w_ih_l0, w_hh_l0, b_l0);
  lstm_fused<128><<<256, 256, 0, stream>>>(bufA, bufB, w_ih_r, w_hh_r, b_r);
  lstm_fused<128><<<256, 256, 0, stream>>>(bufB, bufA, w_ih_r + 65536, w_hh_r + 32768, b_r + 512);
  lstm_fused<128><<<256, 256, 0, stream>>>(bufA, bufB, w_ih_r + 131072, w_hh_r + 65536, b_r + 1024);
  attn_kernel<<<BATCH, 256, 0, stream>>>(bufB, w_attn, pooled);
  head_kernel<<<BATCH, 128, 0, stream>>>(pooled, g1, be1, m1, v1, w1, b1, w2, b2,
                                         g2, be2, m2, v2, w3, b3, out);
}